// Round 1
// baseline (539.419 us; speedup 1.0000x reference)
//
#include <hip/hip_runtime.h>
#include <math.h>

#define S_LEN 512
#define BATCH 256
#define NTAG  128

typedef float f32x4 __attribute__((ext_vector_type(4)));
typedef float f32x2 __attribute__((ext_vector_type(2)));

__device__ __forceinline__ float xmax(float a, float b) { return fmaxf(a, b); }

// swizzled LDS float index: pad 8 floats after every 32 -> h-quarters land on
// disjoint bank groups for the wave's 4 distinct broadcast addresses.
__device__ __forceinline__ int swz(int k) { return k + ((k >> 5) << 3); }

// ---------------------------------------------------------------------------
// Forward (log-partition) + viterbi, one block per batch element.
// 256 threads: p = tid>>2 in [0,64) owns tags j0=2p, j1=2p+1; h = tid&3 owns
// k-quarter [32h, 32h+32). trans rows kept in registers (raw + exp'd).
// ---------------------------------------------------------------------------
__global__ __launch_bounds__(256, 1)
void crf_fwd_kernel(const float* __restrict__ emis,
                    const float* __restrict__ mask,
                    const float* __restrict__ trans,
                    const float* __restrict__ startt,
                    const float* __restrict__ stopt,
                    float* __restrict__ out)
{
  const int b    = blockIdx.x;
  const int tid  = threadIdx.x;
  const int h    = tid & 3;
  const int p    = tid >> 2;
  const int j0   = 2 * p;
  const int lane = tid & 63;
  const int wid  = tid >> 6;

  // double-buffered: [0..151] swizzled w / vv data, [152..155] reduce scratch
  __shared__ __align__(16) float wbuf[2][160];
  __shared__ __align__(16) float vbuf[2][160];

  // ---- load my two transition rows (k in [32h,32h+32)), plus exp'd copy ----
  f32x4 T0[8], T1[8], E0[8], E1[8];
  {
    const f32x4* tr0 = (const f32x4*)(trans + (size_t)j0 * NTAG + 32 * h);
    const f32x4* tr1 = (const f32x4*)(trans + (size_t)(j0 + 1) * NTAG + 32 * h);
#pragma unroll
    for (int c = 0; c < 8; ++c) { T0[c] = tr0[c]; T1[c] = tr1[c]; }
#pragma unroll
    for (int c = 0; c < 8; ++c) {
#pragma unroll
      for (int i = 0; i < 4; ++i) {
        E0[c][i] = __expf(T0[c][i]);
        E1[c][i] = __expf(T1[c][i]);
      }
    }
  }

  // ---- init: fv = vv = start + emissions[0] ----
  f32x2 em2 = *(const f32x2*)(emis + (size_t)b * NTAG + j0);
  f32x2 st2 = *(const f32x2*)(startt + j0);
  float fv0 = st2[0] + em2[0], fv1 = st2[1] + em2[1];
  float vv0 = fv0, vv1 = fv1;

  // block max of init fv -> M0
  {
    float mmx = xmax(fv0, fv1);
    mmx = xmax(mmx, __shfl_xor(mmx, 4));
    mmx = xmax(mmx, __shfl_xor(mmx, 8));
    mmx = xmax(mmx, __shfl_xor(mmx, 16));
    mmx = xmax(mmx, __shfl_xor(mmx, 32));
    if (lane == 0) wbuf[1][152 + wid] = mmx;
  }
  __syncthreads();
  float M0 = xmax(xmax(wbuf[1][152], wbuf[1][153]), xmax(wbuf[1][154], wbuf[1][155]));
  float F  = M0;
  float f0 = fv0 - M0, f1 = fv1 - M0;
  {
    if (h == 0) {
      int i0 = swz(j0);
      wbuf[0][i0]     = __expf(f0);
      wbuf[0][i0 + 1] = __expf(f1);
      vbuf[0][i0]     = vv0;
      vbuf[0][i0 + 1] = vv1;
    }
    if (lane == 0) wbuf[0][152 + wid] = 0.f;  // d-seed for step 1
  }
  __syncthreads();

  // ---- main recurrence ----
  int pb = 0;
  const int base = 10 * h;  // f32x4 chunk base of my k-quarter (swizzled)

  float m = mask[(size_t)BATCH + b];
  m = __shfl(m, 0);  // force wave-uniform
  for (int s = 1; s < S_LEN; ++s) {
    if (m == 0.f) break;
    int sp = (s + 1 < S_LEN) ? (s + 1) : (S_LEN - 1);
    float mnext = mask[(size_t)sp * BATCH + b];
    mnext = __shfl(mnext, 0);

    f32x2 e2 = *(const f32x2*)(emis + ((size_t)s * BATCH + b) * NTAG + j0);

    const f32x4* wr = (const f32x4*)wbuf[pb];
    const f32x4* vr = (const f32x4*)vbuf[pb];
    float d = xmax(xmax(wbuf[pb][152], wbuf[pb][153]),
                   xmax(wbuf[pb][154], wbuf[pb][155]));

    float sum0 = 0.f, sum1 = 0.f;
    float vm0 = -INFINITY, vm1 = -INFINITY;
#pragma unroll
    for (int c = 0; c < 8; ++c) {
      f32x4 wv = wr[base + c];
      f32x4 vq = vr[base + c];
#pragma unroll
      for (int i = 0; i < 4; ++i) {
        sum0 = __builtin_fmaf(E0[c][i], wv[i], sum0);
        sum1 = __builtin_fmaf(E1[c][i], wv[i], sum1);
        vm0  = xmax(vm0, vq[i] + T0[c][i]);
        vm1  = xmax(vm1, vq[i] + T1[c][i]);
      }
    }
    // combine the 4 k-quarters (lanes differ in bits 0,1)
    sum0 += __shfl_xor(sum0, 1); sum0 += __shfl_xor(sum0, 2);
    sum1 += __shfl_xor(sum1, 1); sum1 += __shfl_xor(sum1, 2);
    vm0 = xmax(vm0, __shfl_xor(vm0, 1)); vm0 = xmax(vm0, __shfl_xor(vm0, 2));
    vm1 = xmax(vm1, __shfl_xor(vm1, 1)); vm1 = xmax(vm1, __shfl_xor(vm1, 2));

    float o0 = e2[0] + __logf(sum0);
    float o1 = e2[1] + __logf(sum1);
    vv0 = e2[0] + vm0;
    vv1 = e2[1] + vm1;

    F += d;
    f0 = o0 - d;
    f1 = o1 - d;

    int q = pb ^ 1;
    if (h == 0) {
      int i0 = swz(j0);
      wbuf[q][i0]     = __expf(f0);
      wbuf[q][i0 + 1] = __expf(f1);
      vbuf[q][i0]     = vv0;
      vbuf[q][i0 + 1] = vv1;
    }
    // wave-partial max of o for next step's shift
    float bm = xmax(o0, o1);
    bm = xmax(bm, __shfl_xor(bm, 4));
    bm = xmax(bm, __shfl_xor(bm, 8));
    bm = xmax(bm, __shfl_xor(bm, 16));
    bm = xmax(bm, __shfl_xor(bm, 32));
    if (lane == 0) wbuf[q][152 + wid] = bm;

    __syncthreads();
    pb = q;
    m  = mnext;
  }

  // ---- epilogue: total = F + lse(f + stop), best = max(vv + stop) ----
  f32x2 sp2 = *(const f32x2*)(stopt + j0);
  float a0 = f0 + sp2[0], a1 = f1 + sp2[1];
  float bb = xmax(vv0 + sp2[0], vv1 + sp2[1]);
  float am = xmax(a0, a1);
  am = xmax(am, __shfl_xor(am, 4));
  am = xmax(am, __shfl_xor(am, 8));
  am = xmax(am, __shfl_xor(am, 16));
  am = xmax(am, __shfl_xor(am, 32));
  bb = xmax(bb, __shfl_xor(bb, 4));
  bb = xmax(bb, __shfl_xor(bb, 8));
  bb = xmax(bb, __shfl_xor(bb, 16));
  bb = xmax(bb, __shfl_xor(bb, 32));
  __syncthreads();
  if (lane == 0) { wbuf[0][152 + wid] = am; vbuf[0][152 + wid] = bb; }
  __syncthreads();
  am = xmax(xmax(wbuf[0][152], wbuf[0][153]), xmax(wbuf[0][154], wbuf[0][155]));
  bb = xmax(xmax(vbuf[0][152], vbuf[0][153]), xmax(vbuf[0][154], vbuf[0][155]));

  float e = (h == 0) ? (__expf(a0 - am) + __expf(a1 - am)) : 0.f;
  e += __shfl_xor(e, 1);  e += __shfl_xor(e, 2);
  e += __shfl_xor(e, 4);  e += __shfl_xor(e, 8);
  e += __shfl_xor(e, 16); e += __shfl_xor(e, 32);
  if (lane == 0) wbuf[1][152 + wid] = e;
  __syncthreads();
  if (tid == 0) {
    float sum = (wbuf[1][152] + wbuf[1][153]) + (wbuf[1][154] + wbuf[1][155]);
    out[1 + BATCH + b]     = F + am + __logf(sum);   // total_score
    out[1 + 2 * BATCH + b] = bb;                     // best_path_score
  }
}

// ---------------------------------------------------------------------------
// Gold path score: parallel over s (mask is monotone: prev = tags[s-1],
// final tag = tags[len-1] with len = sum(mask)). One block per batch.
// ---------------------------------------------------------------------------
__global__ __launch_bounds__(256, 1)
void crf_gold_kernel(const float* __restrict__ emis,
                     const float* __restrict__ mask,
                     const int* __restrict__ tags,
                     const float* __restrict__ trans,
                     const float* __restrict__ startt,
                     const float* __restrict__ stopt,
                     float* __restrict__ out)
{
  const int b   = blockIdx.x;
  const int tid = threadIdx.x;
  float part = 0.f, lenp = 0.f;
#pragma unroll
  for (int rep = 0; rep < S_LEN / 256; ++rep) {
    int s = tid + rep * 256;
    float m = mask[(size_t)s * BATCH + b];
    int cur = tags[(size_t)s * BATCH + b];
    if (s == 0) {
      part += startt[cur] + emis[(size_t)b * NTAG + cur] * m;
    } else {
      int prev = tags[(size_t)(s - 1) * BATCH + b];
      part += m * (trans[(size_t)prev * NTAG + cur] +
                   emis[((size_t)s * BATCH + b) * NTAG + cur]);
    }
    lenp += m;
  }
  part += __shfl_xor(part, 1);  part += __shfl_xor(part, 2);
  part += __shfl_xor(part, 4);  part += __shfl_xor(part, 8);
  part += __shfl_xor(part, 16); part += __shfl_xor(part, 32);
  lenp += __shfl_xor(lenp, 1);  lenp += __shfl_xor(lenp, 2);
  lenp += __shfl_xor(lenp, 4);  lenp += __shfl_xor(lenp, 8);
  lenp += __shfl_xor(lenp, 16); lenp += __shfl_xor(lenp, 32);

  __shared__ float rp[4], rl[4];
  const int lane = tid & 63, wid = tid >> 6;
  if (lane == 0) { rp[wid] = part; rl[wid] = lenp; }
  __syncthreads();
  if (tid == 0) {
    float rps = (rp[0] + rp[1]) + (rp[2] + rp[3]);
    int len   = (int)((rl[0] + rl[1]) + (rl[2] + rl[3]) + 0.5f);
    int pf    = tags[(size_t)(len - 1) * BATCH + b];
    out[1 + b] = rps + stopt[pf];  // real_path_score
  }
}

// ---------------------------------------------------------------------------
// loss = mean(total_score - real_path_score)
// ---------------------------------------------------------------------------
__global__ __launch_bounds__(256, 1)
void crf_loss_kernel(float* __restrict__ out)
{
  const int tid = threadIdx.x;
  float dft = out[1 + BATCH + tid] - out[1 + tid];
  dft += __shfl_xor(dft, 1);  dft += __shfl_xor(dft, 2);
  dft += __shfl_xor(dft, 4);  dft += __shfl_xor(dft, 8);
  dft += __shfl_xor(dft, 16); dft += __shfl_xor(dft, 32);
  __shared__ float rs[4];
  const int lane = tid & 63, wid = tid >> 6;
  if (lane == 0) rs[wid] = dft;
  __syncthreads();
  if (tid == 0)
    out[0] = ((rs[0] + rs[1]) + (rs[2] + rs[3])) * (1.0f / BATCH);
}

extern "C" void kernel_launch(void* const* d_in, const int* in_sizes, int n_in,
                              void* d_out, int out_size, void* d_ws, size_t ws_size,
                              hipStream_t stream)
{
  const float* emis   = (const float*)d_in[0];
  const float* mask   = (const float*)d_in[1];
  const int*   tags   = (const int*)d_in[2];
  const float* trans  = (const float*)d_in[3];
  const float* startt = (const float*)d_in[4];
  const float* stopt  = (const float*)d_in[5];
  float* out = (float*)d_out;

  crf_fwd_kernel<<<BATCH, 256, 0, stream>>>(emis, mask, trans, startt, stopt, out);
  crf_gold_kernel<<<BATCH, 256, 0, stream>>>(emis, mask, tags, trans, startt, stopt, out);
  crf_loss_kernel<<<1, 256, 0, stream>>>(out);
}

// Round 2
// 358.328 us; speedup vs baseline: 1.5054x; 1.5054x over previous
//
#include <hip/hip_runtime.h>
#include <math.h>

#define S_LEN 512
#define BATCH 256
#define NTAG  128

typedef float f32x4 __attribute__((ext_vector_type(4)));

// swizzled LDS float index: pad 8 floats after every 32 -> the 4 k-quarters'
// broadcast addresses land on disjoint bank quads.
__device__ __forceinline__ int swz(int k) { return k + ((k >> 5) << 3); }

// DPP quad-perm butterfly (intra-quad, VALU-speed, no LDS pipe)
#define DPP_XOR1(x) __int_as_float(__builtin_amdgcn_mov_dpp(__float_as_int(x), 0xB1, 0xF, 0xF, false))
#define DPP_XOR2(x) __int_as_float(__builtin_amdgcn_mov_dpp(__float_as_int(x), 0x4E, 0xF, 0xF, false))

// ---------------------------------------------------------------------------
// Forward + viterbi in exp space, one block (512 threads) per batch element.
// Thread (j = tid>>2, h = tid&3): row j, k-quarter [32h, 32h+32).
// LDS holds W[k] = exp(fv[k] - Eacc*ln2), V[k] = exp(vv[k] - Eacc_v*ln2),
// renormalized each step by the power-of-2 exponent of max(read values):
//   W'[j] = exp(em[j]) * (sum_k E[j,k] W[k]) * 2^-e,   Eacc += e
//   V'[j] = exp(em[j]) * (max_k E[j,k] V[k]) * 2^-ev,  Eacc_v += ev
// e is derived consumer-side from the very values read -> no producer-side
// reduction, no log/exp on the recurrence critical path.
// ---------------------------------------------------------------------------
__global__ __launch_bounds__(512, 1)
void crf_fwd_kernel(const float* __restrict__ emis,
                    const float* __restrict__ mask,
                    const float* __restrict__ trans,
                    const float* __restrict__ startt,
                    const float* __restrict__ stopt,
                    float* __restrict__ out)
{
  const int b   = blockIdx.x;
  const int tid = threadIdx.x;
  const int h   = tid & 3;
  const int j   = tid >> 2;     // 0..127

  __shared__ __align__(16) float wbuf[2][160];
  __shared__ __align__(16) float vbuf[2][160];

  // E row-quarter in registers: E[j, 32h .. 32h+32)
  f32x4 E[8];
  {
    const float* tr = trans + (size_t)j * NTAG + 32 * h;
#pragma unroll
    for (int c = 0; c < 8; ++c) {
      f32x4 t = *(const f32x4*)(tr + 4 * c);
      E[c][0] = __expf(t[0]); E[c][1] = __expf(t[1]);
      E[c][2] = __expf(t[2]); E[c][3] = __expf(t[3]);
    }
  }

  // init: W0 = V0 = exp(start + em0), C = 0
  {
    float fv0 = startt[j] + emis[(size_t)b * NTAG + j];
    if (h == 0) {
      float u = __expf(fv0);
      wbuf[0][swz(j)] = u;
      vbuf[0][swz(j)] = u;
    }
  }

  int Ew = 0, Ev = 0;
  int pb = 0;
  const int base = 10 * h;   // f32x4 index of my quarter in swizzled buffer

  float m       = mask[(size_t)BATCH + b];
  float em_next = emis[((size_t)1 * BATCH + b) * NTAG + j];
  __syncthreads();

  for (int s = 1; s < S_LEN; ++s) {
    if (m == 0.f) break;
    float ex = __expf(em_next);              // exp(em[s, b, j])
    int sp = (s + 1 < S_LEN) ? (s + 1) : (S_LEN - 1);
    float mnx   = mask[(size_t)sp * BATCH + b];
    float em_nx = emis[((size_t)sp * BATCH + b) * NTAG + j];

    const f32x4* wr = (const f32x4*)wbuf[pb];
    const f32x4* vr = (const f32x4*)vbuf[pb];

    float s0 = 0.f, s1 = 0.f, s2 = 0.f, s3 = 0.f;
    float vm0 = 0.f, vm1 = 0.f;              // all values > 0
    float rw0 = 0.f, rw1 = 0.f;
    float rv0 = 0.f, rv1 = 0.f;
#pragma unroll
    for (int c = 0; c < 8; ++c) {
      f32x4 w = wr[base + c];
      f32x4 v = vr[base + c];
      s0 = __builtin_fmaf(E[c][0], w[0], s0);
      s1 = __builtin_fmaf(E[c][1], w[1], s1);
      s2 = __builtin_fmaf(E[c][2], w[2], s2);
      s3 = __builtin_fmaf(E[c][3], w[3], s3);
      float t0 = E[c][0] * v[0], t1 = E[c][1] * v[1];
      float t2 = E[c][2] * v[2], t3 = E[c][3] * v[3];
      vm0 = fmaxf(fmaxf(vm0, t0), t1);       // -> v_max3
      vm1 = fmaxf(fmaxf(vm1, t2), t3);
      rw0 = fmaxf(fmaxf(rw0, w[0]), w[1]);
      rw1 = fmaxf(fmaxf(rw1, w[2]), w[3]);
      rv0 = fmaxf(fmaxf(rv0, v[0]), v[1]);
      rv1 = fmaxf(fmaxf(rv1, v[2]), v[3]);
    }
    float sum = (s0 + s1) + (s2 + s3);
    float vm  = fmaxf(vm0, vm1);
    float rw  = fmaxf(rw0, rw1);
    float rv  = fmaxf(rv0, rv1);

    // combine the 4 k-quarters (quad lanes) via DPP — VALU latency only
    sum += DPP_XOR1(sum); sum += DPP_XOR2(sum);
    vm = fmaxf(vm, DPP_XOR1(vm)); vm = fmaxf(vm, DPP_XOR2(vm));
    rw = fmaxf(rw, DPP_XOR1(rw)); rw = fmaxf(rw, DPP_XOR2(rw));
    rv = fmaxf(rv, DPP_XOR1(rv)); rv = fmaxf(rv, DPP_XOR2(rv));

    // power-of-2 renorm: e s.t. rw in [2^(e-1), 2^e); scale = 2^-e exactly
    int ew = (int)((__float_as_uint(rw) >> 23) & 0xFF) - 126;
    int ev = (int)((__float_as_uint(rv) >> 23) & 0xFF) - 126;
    float sw = __uint_as_float((unsigned)(127 - ew) << 23);
    float sv = __uint_as_float((unsigned)(127 - ev) << 23);
    Ew += ew; Ev += ev;

    float uf = ex * sum * sw;
    float uv = ex * vm * sv;

    int q = pb ^ 1;
    if (h == 0) {
      wbuf[q][swz(j)] = uf;
      vbuf[q][swz(j)] = uv;
    }
    __syncthreads();
    pb = q;
    m = mnx;
    em_next = em_nx;
  }

  // ---- epilogue ----
  // fv[j] = log W[j] + Ew*ln2 ; total = Ew*ln2 + log(sum_j W[j]*exp(stop_j))
  // vv[j] = log V[j] + Ev*ln2 ; best  = Ev*ln2 + log(max_j V[j]*exp(stop_j))
  float W  = wbuf[pb][swz(j)];
  float V  = vbuf[pb][swz(j)];
  float es = __expf(stopt[j]);
  int q2 = pb ^ 1;
  if (h == 0) {
    wbuf[q2][swz(j)] = W * es;
    vbuf[q2][swz(j)] = V * es;
  }
  __syncthreads();
  if (tid < 64) {
    float sA = wbuf[q2][swz(tid)] + wbuf[q2][swz(tid + 64)];
    float mB = fmaxf(vbuf[q2][swz(tid)], vbuf[q2][swz(tid + 64)]);
#pragma unroll
    for (int d = 1; d <= 32; d <<= 1) {
      sA += __shfl_xor(sA, d);
      mB = fmaxf(mB, __shfl_xor(mB, d));
    }
    if (tid == 0) {
      const double LN2 = 0.6931471805599453;
      out[1 + BATCH + b]     = (float)((double)Ew * LN2 + (double)__logf(sA));
      out[1 + 2 * BATCH + b] = (float)((double)Ev * LN2 + (double)__logf(mB));
    }
  }
}

// ---------------------------------------------------------------------------
// Gold path score (mask monotone: prev tag = tags[s-1], final via len).
// ---------------------------------------------------------------------------
__global__ __launch_bounds__(256, 1)
void crf_gold_kernel(const float* __restrict__ emis,
                     const float* __restrict__ mask,
                     const int* __restrict__ tags,
                     const float* __restrict__ trans,
                     const float* __restrict__ startt,
                     const float* __restrict__ stopt,
                     float* __restrict__ out)
{
  const int b   = blockIdx.x;
  const int tid = threadIdx.x;
  float part = 0.f, lenp = 0.f;
#pragma unroll
  for (int rep = 0; rep < S_LEN / 256; ++rep) {
    int s = tid + rep * 256;
    float m = mask[(size_t)s * BATCH + b];
    int cur = tags[(size_t)s * BATCH + b];
    if (s == 0) {
      part += startt[cur] + emis[(size_t)b * NTAG + cur] * m;
    } else {
      int prev = tags[(size_t)(s - 1) * BATCH + b];
      part += m * (trans[(size_t)prev * NTAG + cur] +
                   emis[((size_t)s * BATCH + b) * NTAG + cur]);
    }
    lenp += m;
  }
  part += __shfl_xor(part, 1);  part += __shfl_xor(part, 2);
  part += __shfl_xor(part, 4);  part += __shfl_xor(part, 8);
  part += __shfl_xor(part, 16); part += __shfl_xor(part, 32);
  lenp += __shfl_xor(lenp, 1);  lenp += __shfl_xor(lenp, 2);
  lenp += __shfl_xor(lenp, 4);  lenp += __shfl_xor(lenp, 8);
  lenp += __shfl_xor(lenp, 16); lenp += __shfl_xor(lenp, 32);

  __shared__ float rp[4], rl[4];
  const int lane = tid & 63, wid = tid >> 6;
  if (lane == 0) { rp[wid] = part; rl[wid] = lenp; }
  __syncthreads();
  if (tid == 0) {
    float rps = (rp[0] + rp[1]) + (rp[2] + rp[3]);
    int len   = (int)((rl[0] + rl[1]) + (rl[2] + rl[3]) + 0.5f);
    int pf    = tags[(size_t)(len - 1) * BATCH + b];
    out[1 + b] = rps + stopt[pf];
  }
}

// ---------------------------------------------------------------------------
// loss = mean(total_score - real_path_score)
// ---------------------------------------------------------------------------
__global__ __launch_bounds__(256, 1)
void crf_loss_kernel(float* __restrict__ out)
{
  const int tid = threadIdx.x;
  float dft = out[1 + BATCH + tid] - out[1 + tid];
  dft += __shfl_xor(dft, 1);  dft += __shfl_xor(dft, 2);
  dft += __shfl_xor(dft, 4);  dft += __shfl_xor(dft, 8);
  dft += __shfl_xor(dft, 16); dft += __shfl_xor(dft, 32);
  __shared__ float rs[4];
  const int lane = tid & 63, wid = tid >> 6;
  if (lane == 0) rs[wid] = dft;
  __syncthreads();
  if (tid == 0)
    out[0] = ((rs[0] + rs[1]) + (rs[2] + rs[3])) * (1.0f / BATCH);
}

extern "C" void kernel_launch(void* const* d_in, const int* in_sizes, int n_in,
                              void* d_out, int out_size, void* d_ws, size_t ws_size,
                              hipStream_t stream)
{
  const float* emis   = (const float*)d_in[0];
  const float* mask   = (const float*)d_in[1];
  const int*   tags   = (const int*)d_in[2];
  const float* trans  = (const float*)d_in[3];
  const float* startt = (const float*)d_in[4];
  const float* stopt  = (const float*)d_in[5];
  float* out = (float*)d_out;

  crf_fwd_kernel<<<BATCH, 512, 0, stream>>>(emis, mask, trans, startt, stopt, out);
  crf_gold_kernel<<<BATCH, 256, 0, stream>>>(emis, mask, tags, trans, startt, stopt, out);
  crf_loss_kernel<<<1, 256, 0, stream>>>(out);
}

// Round 3
// 262.795 us; speedup vs baseline: 2.0526x; 1.3635x over previous
//
#include <hip/hip_runtime.h>
#include <math.h>

#define S_LEN 512
#define BATCH 256
#define NTAG  128
#define EMSTRIDE (BATCH * NTAG)  /* floats per time step */

typedef float f32x4 __attribute__((ext_vector_type(4)));

// swizzled LDS float index: pad 8 floats after every 32 -> the 4 k-quarters'
// broadcast addresses land on disjoint bank quads.
__device__ __forceinline__ int swz(int k) { return k + ((k >> 5) << 3); }

// DPP quad-perm butterfly (intra-quad, VALU-speed, no LDS pipe)
#define DPP_XOR1(x) __int_as_float(__builtin_amdgcn_mov_dpp(__float_as_int(x), 0xB1, 0xF, 0xF, false))
#define DPP_XOR2(x) __int_as_float(__builtin_amdgcn_mov_dpp(__float_as_int(x), 0x4E, 0xF, 0xF, false))

// Raw barrier: drain LDS ops only (NOT vmcnt) so global prefetch loads stay
// in flight across steps. sched_barrier stops compiler motion across it.
#define BAR() do {                                       \
    asm volatile("s_waitcnt lgkmcnt(0)" ::: "memory");   \
    __builtin_amdgcn_s_barrier();                        \
    __builtin_amdgcn_sched_barrier(0);                   \
  } while (0)

// ---------------------------------------------------------------------------
// Forward + viterbi in exp space, one block (512 threads) per batch element.
// Thread (j = tid>>2, h = tid&3): row j, k-quarter [32h, 32h+32).
// W[k] = exp(fv[k] - Ew*ln2), V[k] = exp(vv[k] - Ev*ln2); power-of-2 renorm
// every 4th step from consumer-side maxima. Steps run in groups of 4 with
// static register slots for a depth-4 emission prefetch.
// ---------------------------------------------------------------------------
__global__ __launch_bounds__(512, 1)
void crf_fwd_kernel(const float* __restrict__ emis,
                    const float* __restrict__ mask,
                    const float* __restrict__ trans,
                    const float* __restrict__ startt,
                    const float* __restrict__ stopt,
                    float* __restrict__ out)
{
  const int b    = blockIdx.x;
  const int tid  = threadIdx.x;
  const int h    = tid & 3;
  const int j    = tid >> 2;     // 0..127
  const int lane = tid & 63;
  const int wid  = tid >> 6;

  __shared__ __align__(16) float wbuf[2][160];
  __shared__ __align__(16) float vbuf[2][160];
  __shared__ float red[16];

  // ---- E row-quarter in registers: exp(trans[j, 32h .. 32h+32)) ----
  f32x4 E[8];
  {
    const float* tr = trans + (size_t)j * NTAG + 32 * h;
#pragma unroll
    for (int c = 0; c < 8; ++c) {
      f32x4 t = *(const f32x4*)(tr + 4 * c);
      E[c][0] = __expf(t[0]); E[c][1] = __expf(t[1]);
      E[c][2] = __expf(t[2]); E[c][3] = __expf(t[3]);
    }
  }

  // ---- len = sum_s mask[s,b] (mask monotone); tid indexes s directly ----
  int len;
  {
    float mv = mask[(size_t)tid * BATCH + b];
#pragma unroll
    for (int d = 1; d <= 32; d <<= 1) mv += __shfl_xor(mv, d);
    if (lane == 0) red[wid] = mv;
    __syncthreads();
    float lsum = 0.f;
#pragma unroll
    for (int w = 0; w < 8; ++w) lsum += red[w];
    len = (int)(lsum + 0.5f);
    len = __builtin_amdgcn_readfirstlane(len);
  }

  // ---- init: W0 = V0 = exp(start + em0) in buf 0 ----
  if (h == 0) {
    float u = __expf(startt[j] + emis[(size_t)b * NTAG + j]);
    wbuf[0][swz(j)] = u;
    vbuf[0][swz(j)] = u;
  }

  // ---- emission prefetch, steps 1..4 (clamped) ----
  const float* eb = emis + (size_t)b * NTAG + j;
  float e0 = eb[(size_t)1 * EMSTRIDE];
  float e1 = eb[(size_t)2 * EMSTRIDE];
  float e2 = eb[(size_t)3 * EMSTRIDE];
  float e3 = eb[(size_t)4 * EMSTRIDE];

  int Ew = 0, Ev = 0;
  int fin = 0;
  const int base = 10 * h;  // f32x4 chunk index of my k-quarter (swizzled)

  __syncthreads();  // init writes visible; one-time full barrier is fine

#define SUBSTEP(U, EMV, RENORM)                                              \
  {                                                                          \
    if (g + (U) >= len) { fin = (U) & 1; goto epi; }                         \
    const f32x4* wr = (const f32x4*)wbuf[(U) & 1];                           \
    const f32x4* vr = (const f32x4*)vbuf[(U) & 1];                           \
    float s0 = 0.f, s1 = 0.f, s2 = 0.f, s3 = 0.f;                            \
    float vm0 = 0.f, vm1 = 0.f, rw = 0.f, rv = 0.f;                          \
    _Pragma("unroll")                                                        \
    for (int c = 0; c < 8; ++c) {                                            \
      f32x4 w = wr[base + c];                                                \
      f32x4 v = vr[base + c];                                                \
      s0 = __builtin_fmaf(E[c][0], w[0], s0);                                \
      s1 = __builtin_fmaf(E[c][1], w[1], s1);                                \
      s2 = __builtin_fmaf(E[c][2], w[2], s2);                                \
      s3 = __builtin_fmaf(E[c][3], w[3], s3);                                \
      vm0 = fmaxf(fmaxf(vm0, E[c][0] * v[0]), E[c][1] * v[1]);               \
      vm1 = fmaxf(fmaxf(vm1, E[c][2] * v[2]), E[c][3] * v[3]);               \
      if (RENORM) {                                                          \
        rw = fmaxf(fmaxf(rw, w[0]), w[1]); rw = fmaxf(fmaxf(rw, w[2]), w[3]);\
        rv = fmaxf(fmaxf(rv, v[0]), v[1]); rv = fmaxf(fmaxf(rv, v[2]), v[3]);\
      }                                                                      \
    }                                                                        \
    float ex  = __expf(EMV);                                                 \
    float sum = (s0 + s1) + (s2 + s3);                                       \
    sum += DPP_XOR1(sum); sum += DPP_XOR2(sum);                              \
    float vm = fmaxf(vm0, vm1);                                              \
    vm = fmaxf(vm, DPP_XOR1(vm)); vm = fmaxf(vm, DPP_XOR2(vm));              \
    float uf, uv;                                                            \
    if (RENORM) {                                                            \
      rw = fmaxf(rw, DPP_XOR1(rw)); rw = fmaxf(rw, DPP_XOR2(rw));            \
      rv = fmaxf(rv, DPP_XOR1(rv)); rv = fmaxf(rv, DPP_XOR2(rv));            \
      int ew = (int)((__float_as_uint(rw) >> 23) & 0xFF) - 126;              \
      int ev = (int)((__float_as_uint(rv) >> 23) & 0xFF) - 126;              \
      Ew += ew; Ev += ev;                                                    \
      float sw = __uint_as_float((unsigned)(127 - ew) << 23);                \
      float sv = __uint_as_float((unsigned)(127 - ev) << 23);                \
      uf = ex * sum * sw; uv = ex * vm * sv;                                 \
    } else {                                                                 \
      uf = ex * sum; uv = ex * vm;                                           \
    }                                                                        \
    if (h == 0) {                                                            \
      wbuf[((U) + 1) & 1][swz(j)] = uf;                                      \
      vbuf[((U) + 1) & 1][swz(j)] = uv;                                      \
    }                                                                        \
    BAR();                                                                   \
  }

  for (int g = 1; g < S_LEN; g += 4) {
    // issue next group's emission loads (stay in flight across raw barriers)
    int c0 = g + 4, c1 = g + 5, c2 = g + 6, c3 = g + 7;
    c0 = c0 < S_LEN ? c0 : S_LEN - 1;
    c1 = c1 < S_LEN ? c1 : S_LEN - 1;
    c2 = c2 < S_LEN ? c2 : S_LEN - 1;
    c3 = c3 < S_LEN ? c3 : S_LEN - 1;
    float n0 = eb[(size_t)c0 * EMSTRIDE];
    float n1 = eb[(size_t)c1 * EMSTRIDE];
    float n2 = eb[(size_t)c2 * EMSTRIDE];
    float n3 = eb[(size_t)c3 * EMSTRIDE];

    SUBSTEP(0, e0, 0)
    SUBSTEP(1, e1, 0)
    SUBSTEP(2, e2, 0)
    SUBSTEP(3, e3, 1)   // renorm once per 4 steps (growth < 2^92, fp32-safe)

    e0 = n0; e1 = n1; e2 = n2; e3 = n3;
  }
  fin = 0;  // not reached (loop always exits via goto), keeps compiler happy

epi:
  // total = Ew*ln2 + log(sum_j W[j]*exp(stop_j)); best = Ev*ln2 + log(max ...)
  {
    float W  = wbuf[fin][swz(j)];
    float V  = vbuf[fin][swz(j)];
    float es = __expf(stopt[j]);
    int q2 = fin ^ 1;
    if (h == 0) {
      wbuf[q2][swz(j)] = W * es;
      vbuf[q2][swz(j)] = V * es;
    }
    __syncthreads();
    if (tid < 64) {
      float sA = wbuf[q2][swz(tid)] + wbuf[q2][swz(tid + 64)];
      float mB = fmaxf(vbuf[q2][swz(tid)], vbuf[q2][swz(tid + 64)]);
#pragma unroll
      for (int d = 1; d <= 32; d <<= 1) {
        sA += __shfl_xor(sA, d);
        mB = fmaxf(mB, __shfl_xor(mB, d));
      }
      if (tid == 0) {
        const double LN2 = 0.6931471805599453;
        out[1 + BATCH + b]     = (float)((double)Ew * LN2 + (double)__logf(sA));
        out[1 + 2 * BATCH + b] = (float)((double)Ev * LN2 + (double)__logf(mB));
      }
    }
  }
}

// ---------------------------------------------------------------------------
// Gold path score (mask monotone: prev tag = tags[s-1], final via len).
// 512 threads: thread == time step.
// ---------------------------------------------------------------------------
__global__ __launch_bounds__(512, 1)
void crf_gold_kernel(const float* __restrict__ emis,
                     const float* __restrict__ mask,
                     const int* __restrict__ tags,
                     const float* __restrict__ trans,
                     const float* __restrict__ startt,
                     const float* __restrict__ stopt,
                     float* __restrict__ out)
{
  const int b = blockIdx.x;
  const int s = threadIdx.x;
  float m  = mask[(size_t)s * BATCH + b];
  int  cur = tags[(size_t)s * BATCH + b];
  float part, lenp = m;
  if (s == 0) {
    part = startt[cur] + emis[(size_t)b * NTAG + cur] * m;
  } else {
    int prev = tags[(size_t)(s - 1) * BATCH + b];
    part = m * (trans[(size_t)prev * NTAG + cur] +
                emis[((size_t)s * BATCH + b) * NTAG + cur]);
  }
#pragma unroll
  for (int d = 1; d <= 32; d <<= 1) {
    part += __shfl_xor(part, d);
    lenp += __shfl_xor(lenp, d);
  }
  __shared__ float rp[8], rl[8];
  const int lane = s & 63, wid = s >> 6;
  if (lane == 0) { rp[wid] = part; rl[wid] = lenp; }
  __syncthreads();
  if (s == 0) {
    float rps = 0.f, lf = 0.f;
#pragma unroll
    for (int w = 0; w < 8; ++w) { rps += rp[w]; lf += rl[w]; }
    int len = (int)(lf + 0.5f);
    int pf  = tags[(size_t)(len - 1) * BATCH + b];
    out[1 + b] = rps + stopt[pf];
  }
}

// ---------------------------------------------------------------------------
// loss = mean(total_score - real_path_score)
// ---------------------------------------------------------------------------
__global__ __launch_bounds__(256, 1)
void crf_loss_kernel(float* __restrict__ out)
{
  const int tid = threadIdx.x;
  float dft = out[1 + BATCH + tid] - out[1 + tid];
#pragma unroll
  for (int d = 1; d <= 32; d <<= 1) dft += __shfl_xor(dft, d);
  __shared__ float rs[4];
  const int lane = tid & 63, wid = tid >> 6;
  if (lane == 0) rs[wid] = dft;
  __syncthreads();
  if (tid == 0)
    out[0] = ((rs[0] + rs[1]) + (rs[2] + rs[3])) * (1.0f / BATCH);
}

extern "C" void kernel_launch(void* const* d_in, const int* in_sizes, int n_in,
                              void* d_out, int out_size, void* d_ws, size_t ws_size,
                              hipStream_t stream)
{
  const float* emis   = (const float*)d_in[0];
  const float* mask   = (const float*)d_in[1];
  const int*   tags   = (const int*)d_in[2];
  const float* trans  = (const float*)d_in[3];
  const float* startt = (const float*)d_in[4];
  const float* stopt  = (const float*)d_in[5];
  float* out = (float*)d_out;

  crf_fwd_kernel<<<BATCH, 512, 0, stream>>>(emis, mask, trans, startt, stopt, out);
  crf_gold_kernel<<<BATCH, 512, 0, stream>>>(emis, mask, tags, trans, startt, stopt, out);
  crf_loss_kernel<<<1, 256, 0, stream>>>(out);
}

// Round 4
// 209.163 us; speedup vs baseline: 2.5789x; 1.2564x over previous
//
#include <hip/hip_runtime.h>
#include <math.h>

#define S_LEN 512
#define BATCH 256
#define NTAG  128
#define EMSTRIDE (BATCH * NTAG)  /* floats per time step */

typedef float f32x4 __attribute__((ext_vector_type(4)));

// swizzled LDS float index: pad 8 floats after every 32 -> the 4 k-quarters'
// broadcast addresses land on disjoint bank quads.
__device__ __forceinline__ int swz(int k) { return k + ((k >> 5) << 3); }

// DPP quad-perm butterfly (intra-quad, VALU-speed, no LDS pipe)
#define DPP_XOR1(x) __int_as_float(__builtin_amdgcn_mov_dpp(__float_as_int(x), 0xB1, 0xF, 0xF, false))
#define DPP_XOR2(x) __int_as_float(__builtin_amdgcn_mov_dpp(__float_as_int(x), 0x4E, 0xF, 0xF, false))

// Raw barrier: drain LDS ops only (NOT vmcnt) so global prefetch loads stay
// in flight across steps. sched_barrier stops compiler motion across it.
#define BAR() do {                                       \
    asm volatile("s_waitcnt lgkmcnt(0)" ::: "memory");   \
    __builtin_amdgcn_s_barrier();                        \
    __builtin_amdgcn_sched_barrier(0);                   \
  } while (0)

__device__ __forceinline__ float max3f(float a, float b, float c) {
  return fmaxf(fmaxf(a, b), c);   // -> v_max3_f32
}

// ---------------------------------------------------------------------------
// Fat kernel, 512 threads/block, grid = 768:
//   blk in [0,512): b = blk>>1; blk&1==0 -> forward role, ==1 -> viterbi role
//   blk in [512,768): gold-path role, b = blk-512
// Forward (exp space, power-of-2 renorm every 4th step) and viterbi (log
// space, no renorm, fp32-bounded) are INDEPENDENT recurrences -> separate
// blocks with separate barriers; their waves interleave on each SIMD and
// hide each other's LDS/barrier latency.
// Thread mapping (recurrence roles): j = tid>>2 (row), h = tid&3 (k-quarter).
// ---------------------------------------------------------------------------
__global__ __launch_bounds__(512, 1)
void crf_fat_kernel(const float* __restrict__ emis,
                    const float* __restrict__ mask,
                    const int* __restrict__ tags,
                    const float* __restrict__ trans,
                    const float* __restrict__ startt,
                    const float* __restrict__ stopt,
                    float* __restrict__ out)
{
  const int blk = blockIdx.x;
  const int tid = threadIdx.x;

  __shared__ __align__(16) float sbuf[2][160];
  __shared__ float red[16];

  // ---------------- gold role ----------------
  if (blk >= 2 * BATCH) {
    const int b = blk - 2 * BATCH;
    const int s = tid;
    float m  = mask[(size_t)s * BATCH + b];
    int  cur = tags[(size_t)s * BATCH + b];
    float part, lenp = m;
    if (s == 0) {
      part = startt[cur] + emis[(size_t)b * NTAG + cur] * m;
    } else {
      int prev = tags[(size_t)(s - 1) * BATCH + b];
      part = m * (trans[(size_t)prev * NTAG + cur] +
                  emis[((size_t)s * BATCH + b) * NTAG + cur]);
    }
#pragma unroll
    for (int d = 1; d <= 32; d <<= 1) {
      part += __shfl_xor(part, d);
      lenp += __shfl_xor(lenp, d);
    }
    const int glane = tid & 63, gwid = tid >> 6;
    if (glane == 0) { red[gwid] = part; red[8 + gwid] = lenp; }
    __syncthreads();
    if (tid == 0) {
      float rps = 0.f, lf = 0.f;
#pragma unroll
      for (int w = 0; w < 8; ++w) { rps += red[w]; lf += red[8 + w]; }
      int len = (int)(lf + 0.5f);
      int pf  = tags[(size_t)(len - 1) * BATCH + b];
      out[1 + b] = rps + stopt[pf];
    }
    return;
  }

  const int b    = blk >> 1;
  const int role = blk & 1;
  const int h    = tid & 3;
  const int j    = tid >> 2;     // 0..127
  const int lane = tid & 63;
  const int wid  = tid >> 6;
  const int base = 10 * h;       // f32x4 chunk index of my quarter (swizzled)

  // ---- len = sum_s mask[s,b] (mask monotone) ----
  int len;
  {
    float mv = mask[(size_t)tid * BATCH + b];
#pragma unroll
    for (int d = 1; d <= 32; d <<= 1) mv += __shfl_xor(mv, d);
    if (lane == 0) red[wid] = mv;
    __syncthreads();
    float ls = 0.f;
#pragma unroll
    for (int w = 0; w < 8; ++w) ls += red[w];
    len = (int)(ls + 0.5f);
    len = __builtin_amdgcn_readfirstlane(len);
  }

  const float* eb = emis + (size_t)b * NTAG + j;

  if (role == 0) {
    // ================= forward (exp space) =================
    f32x4 E[8];
    {
      const float* tr = trans + (size_t)j * NTAG + 32 * h;
#pragma unroll
      for (int c = 0; c < 8; ++c) {
        f32x4 t = *(const f32x4*)(tr + 4 * c);
        E[c][0] = __expf(t[0]); E[c][1] = __expf(t[1]);
        E[c][2] = __expf(t[2]); E[c][3] = __expf(t[3]);
      }
    }
    if (h == 0) sbuf[0][swz(j)] = __expf(startt[j] + eb[0]);

    float e0 = eb[(size_t)1 * EMSTRIDE];
    float e1 = eb[(size_t)2 * EMSTRIDE];
    float e2 = eb[(size_t)3 * EMSTRIDE];
    float e3 = eb[(size_t)4 * EMSTRIDE];

    int Ew = 0, fin = 0;
    __syncthreads();

#define FSTEP(U, EMV, RENORM)                                                \
  {                                                                          \
    if (g + (U) >= len) { fin = (U) & 1; goto epi_f; }                       \
    const f32x4* wr = (const f32x4*)sbuf[(U) & 1];                           \
    float s0 = 0.f, s1 = 0.f, s2 = 0.f, s3 = 0.f, rw = 0.f;                  \
    _Pragma("unroll")                                                        \
    for (int c = 0; c < 8; ++c) {                                            \
      f32x4 w = wr[base + c];                                                \
      s0 = __builtin_fmaf(E[c][0], w[0], s0);                                \
      s1 = __builtin_fmaf(E[c][1], w[1], s1);                                \
      s2 = __builtin_fmaf(E[c][2], w[2], s2);                                \
      s3 = __builtin_fmaf(E[c][3], w[3], s3);                                \
      if (RENORM) { rw = max3f(rw, w[0], w[1]); rw = max3f(rw, w[2], w[3]); }\
    }                                                                        \
    float ex  = __expf(EMV);                                                 \
    float sum = (s0 + s1) + (s2 + s3);                                       \
    sum += DPP_XOR1(sum); sum += DPP_XOR2(sum);                              \
    float uf;                                                                \
    if (RENORM) {                                                            \
      rw = fmaxf(rw, DPP_XOR1(rw)); rw = fmaxf(rw, DPP_XOR2(rw));            \
      int ew = (int)((__float_as_uint(rw) >> 23) & 0xFF) - 126;              \
      Ew += ew;                                                              \
      float sw = __uint_as_float((unsigned)(127 - ew) << 23);                \
      uf = ex * sum * sw;                                                    \
    } else {                                                                 \
      uf = ex * sum;                                                         \
    }                                                                        \
    if (h == 0) sbuf[((U) + 1) & 1][swz(j)] = uf;                            \
    BAR();                                                                   \
  }

    for (int g = 1; g < S_LEN; g += 4) {
      int c0 = g + 4, c1 = g + 5, c2 = g + 6, c3 = g + 7;
      c0 = c0 < S_LEN ? c0 : S_LEN - 1;
      c1 = c1 < S_LEN ? c1 : S_LEN - 1;
      c2 = c2 < S_LEN ? c2 : S_LEN - 1;
      c3 = c3 < S_LEN ? c3 : S_LEN - 1;
      float n0 = eb[(size_t)c0 * EMSTRIDE];
      float n1 = eb[(size_t)c1 * EMSTRIDE];
      float n2 = eb[(size_t)c2 * EMSTRIDE];
      float n3 = eb[(size_t)c3 * EMSTRIDE];

      FSTEP(0, e0, 0)
      FSTEP(1, e1, 0)
      FSTEP(2, e2, 0)
      FSTEP(3, e3, 1)   // renorm every 4th step (growth < 2^80, fp32-safe)

      e0 = n0; e1 = n1; e2 = n2; e3 = n3;
    }
    fin = 0;

epi_f:
    {
      float W  = sbuf[fin][swz(j)];
      float es = __expf(stopt[j]);
      int q2 = fin ^ 1;
      if (h == 0) sbuf[q2][swz(j)] = W * es;
      __syncthreads();
      if (tid < 64) {
        float sA = sbuf[q2][swz(tid)] + sbuf[q2][swz(tid + 64)];
#pragma unroll
        for (int d = 1; d <= 32; d <<= 1) sA += __shfl_xor(sA, d);
        if (tid == 0) {
          const double LN2 = 0.6931471805599453;
          out[1 + BATCH + b] = (float)((double)Ew * LN2 + (double)__logf(sA));
        }
      }
    }
  } else {
    // ================= viterbi (log space, no renorm) =================
    f32x4 T[8];
    {
      const float* tr = trans + (size_t)j * NTAG + 32 * h;
#pragma unroll
      for (int c = 0; c < 8; ++c) T[c] = *(const f32x4*)(tr + 4 * c);
    }
    if (h == 0) sbuf[0][swz(j)] = startt[j] + eb[0];

    float e0 = eb[(size_t)1 * EMSTRIDE];
    float e1 = eb[(size_t)2 * EMSTRIDE];
    float e2 = eb[(size_t)3 * EMSTRIDE];
    float e3 = eb[(size_t)4 * EMSTRIDE];

    int fin = 0;
    __syncthreads();

#define VSTEP(U, EMV)                                                        \
  {                                                                          \
    if (g + (U) >= len) { fin = (U) & 1; goto epi_v; }                       \
    const f32x4* vr = (const f32x4*)sbuf[(U) & 1];                           \
    float vmA = -3.0e38f, vmB = -3.0e38f;                                    \
    _Pragma("unroll")                                                        \
    for (int c = 0; c < 8; ++c) {                                            \
      f32x4 v = vr[base + c];                                                \
      vmA = max3f(vmA, v[0] + T[c][0], v[1] + T[c][1]);                      \
      vmB = max3f(vmB, v[2] + T[c][2], v[3] + T[c][3]);                      \
    }                                                                        \
    float vm = fmaxf(vmA, vmB);                                              \
    vm = fmaxf(vm, DPP_XOR1(vm)); vm = fmaxf(vm, DPP_XOR2(vm));              \
    float uv = EMV + vm;                                                     \
    if (h == 0) sbuf[((U) + 1) & 1][swz(j)] = uv;                            \
    BAR();                                                                   \
  }

    for (int g = 1; g < S_LEN; g += 4) {
      int c0 = g + 4, c1 = g + 5, c2 = g + 6, c3 = g + 7;
      c0 = c0 < S_LEN ? c0 : S_LEN - 1;
      c1 = c1 < S_LEN ? c1 : S_LEN - 1;
      c2 = c2 < S_LEN ? c2 : S_LEN - 1;
      c3 = c3 < S_LEN ? c3 : S_LEN - 1;
      float n0 = eb[(size_t)c0 * EMSTRIDE];
      float n1 = eb[(size_t)c1 * EMSTRIDE];
      float n2 = eb[(size_t)c2 * EMSTRIDE];
      float n3 = eb[(size_t)c3 * EMSTRIDE];

      VSTEP(0, e0)
      VSTEP(1, e1)
      VSTEP(2, e2)
      VSTEP(3, e3)

      e0 = n0; e1 = n1; e2 = n2; e3 = n3;
    }
    fin = 0;

epi_v:
    {
      float V = sbuf[fin][swz(j)];
      float a = V + stopt[j];
      int q2 = fin ^ 1;
      if (h == 0) sbuf[q2][swz(j)] = a;
      __syncthreads();
      if (tid < 64) {
        float mB = fmaxf(sbuf[q2][swz(tid)], sbuf[q2][swz(tid + 64)]);
#pragma unroll
        for (int d = 1; d <= 32; d <<= 1) mB = fmaxf(mB, __shfl_xor(mB, d));
        if (tid == 0) out[1 + 2 * BATCH + b] = mB;
      }
    }
  }
}

// ---------------------------------------------------------------------------
// loss = mean(total_score - real_path_score)
// ---------------------------------------------------------------------------
__global__ __launch_bounds__(256, 1)
void crf_loss_kernel(float* __restrict__ out)
{
  const int tid = threadIdx.x;
  float dft = out[1 + BATCH + tid] - out[1 + tid];
#pragma unroll
  for (int d = 1; d <= 32; d <<= 1) dft += __shfl_xor(dft, d);
  __shared__ float rs[4];
  const int lane = tid & 63, wid = tid >> 6;
  if (lane == 0) rs[wid] = dft;
  __syncthreads();
  if (tid == 0)
    out[0] = ((rs[0] + rs[1]) + (rs[2] + rs[3])) * (1.0f / BATCH);
}

extern "C" void kernel_launch(void* const* d_in, const int* in_sizes, int n_in,
                              void* d_out, int out_size, void* d_ws, size_t ws_size,
                              hipStream_t stream)
{
  const float* emis   = (const float*)d_in[0];
  const float* mask   = (const float*)d_in[1];
  const int*   tags   = (const int*)d_in[2];
  const float* trans  = (const float*)d_in[3];
  const float* startt = (const float*)d_in[4];
  const float* stopt  = (const float*)d_in[5];
  float* out = (float*)d_out;

  crf_fat_kernel<<<3 * BATCH, 512, 0, stream>>>(emis, mask, tags, trans,
                                                startt, stopt, out);
  crf_loss_kernel<<<1, 256, 0, stream>>>(out);
}